// Round 2
// 353.768 us; speedup vs baseline: 1.0260x; 1.0260x over previous
//
#include <hip/hip_runtime.h>

#define N_    16
#define M_    100
#define L_    10000
#define EMB_  128
#define TL    64     // l-tile
#define NT    256    // 4 waves
#define MT    112    // m padded to 7 tiles of 16
#define BDP   136    // B_s row stride in f16 (128+8)
#define DWP   68     // dw_s row stride in f16 (64+4)
#define NIT   25     // (TL*M_)/NT float4 loads per thread per tile
#define NTILES 157   // ceil(L_/TL)
#define NBX   32     // blocks per n -> 512 blocks total = exactly 2/CU, 64/XCD

typedef _Float16 half8   __attribute__((ext_vector_type(8)));
typedef _Float16 half4v  __attribute__((ext_vector_type(4)));
typedef float    floatx4 __attribute__((ext_vector_type(4)));

// Persistent-strided blocks: each block stages B_s = attn[n]*w ONCE, then
// walks tiles t = bx, bx+32, ... with a register-level delta double-buffer:
// tile t+32's 25 float4 loads are in flight while tile t is MFMA'd+combined.
__global__ __launch_bounds__(NT, 2) void attn_fused_kernel(
    const float* __restrict__ self_attn,   // (N, M, EMB)
    const float* __restrict__ self_delta,  // (N, M, L, 4)
    const float* __restrict__ emb_table,   // (L+1, EMB)
    const float* __restrict__ value_w,     // (M)
    float* __restrict__ out)               // (N, L)
{
    __shared__ _Float16 B_s[MT * BDP];    // attnw[m][d], f16   (30.5 KB)
    __shared__ _Float16 dw_s[MT * DWP];   // dw[m][ll],  f16   (15.2 KB)

    const int n   = blockIdx.y;
    const int bx  = blockIdx.x;
    const int tid = threadIdx.x;

    const floatx4* dp = (const floatx4*)self_delta + (size_t)n * M_ * L_;

    // ---- 1. Issue tile bx's delta loads first (deep MLP under the staging).
    //         Nontemporal: delta is a 256 MB stream-once — keep emb/attn in L2.
    floatx4 dv[NIT];
    {
        const int l0 = bx * TL;
        #pragma unroll
        for (int it = 0; it < NIT; ++it) {
            int idx = tid + it * NT;
            int ll  = idx & (TL - 1);
            int m   = idx >> 6;
            int l   = l0 + ll;
            floatx4 z = {0.f, 0.f, 0.f, 0.f};
            dv[it] = (l < L_) ? __builtin_nontemporal_load(&dp[(size_t)m * L_ + l]) : z;
        }
    }

    // ---- 2. Zero pad rows m=100..111 of both LDS panels (once) ----
    for (int i = tid; i < 12 * BDP; i += NT)
        B_s[100 * BDP + i] = (_Float16)0.f;
    for (int i = tid; i < 12 * DWP; i += NT)
        dw_s[100 * DWP + i] = (_Float16)0.f;

    // ---- 3. Stage B_s = attn[n,m,:] * w[m] as f16, ONCE per block (L2-hot) ----
    const float4* ap = (const float4*)(self_attn + (size_t)n * M_ * EMB_);
    for (int i = tid; i < M_ * EMB_ / 4; i += NT) {
        int m  = i >> 5;            // (i*4) / 128
        int d4 = (i & 31) * 4;
        float wv  = value_w[m];
        float4 av = ap[i];
        half4v h;
        h[0] = (_Float16)(av.x * wv); h[1] = (_Float16)(av.y * wv);
        h[2] = (_Float16)(av.z * wv); h[3] = (_Float16)(av.w * wv);
        *(half4v*)&B_s[m * BDP + d4] = h;   // 8B-aligned ds_write_b64
    }

    const int lane  = tid & 63;
    const int wid   = tid >> 6;     // wave's 16-row l-subtile
    const int row   = lane & 15;
    const int q     = lane >> 4;
    const int lbase = wid * 16 + q * 4;

    for (int t = bx; t < NTILES; t += NBX) {
        const int l0 = t * TL;

        // ---- 4. Reduce this tile's float4s -> dw_s[m][ll] (writes conflict-free) ----
        #pragma unroll
        for (int it = 0; it < NIT; ++it) {
            int idx = tid + it * NT;
            int ll  = idx & (TL - 1);
            int m   = idx >> 6;
            floatx4 d4 = dv[it];
            dw_s[m * DWP + ll] = (_Float16)(d4.x + d4.y + d4.z + d4.w);
        }
        __syncthreads();   // dw_s (and, first iter, B_s) visible to all waves

        // ---- 5. Prefetch next tile's delta NOW — in flight across MFMA+epilogue ----
        const int tn = t + NBX;
        if (tn < NTILES) {
            const int l0n = tn * TL;
            #pragma unroll
            for (int it = 0; it < NIT; ++it) {
                int idx = tid + it * NT;
                int ll  = idx & (TL - 1);
                int m   = idx >> 6;
                int l   = l0n + ll;
                floatx4 z = {0.f, 0.f, 0.f, 0.f};
                dv[it] = (l < L_) ? __builtin_nontemporal_load(&dp[(size_t)m * L_ + l]) : z;
            }
        }

        // ---- 6. MFMA: s[l,m] tiles. A = emb rows (f32->f16, L2-hot), B = B_s ----
        floatx4 acc[7];
        #pragma unroll
        for (int tt = 0; tt < 7; ++tt) acc[tt] = (floatx4){0.f, 0.f, 0.f, 0.f};

        int al = l0 + wid * 16 + row + 1;        // emb row = l+1
        if (al > L_) al = L_;                    // clamp (dw=0 kills the product)
        const float* ep = emb_table + (size_t)al * EMB_ + q * 8;

        #pragma unroll
        for (int kc = 0; kc < 4; ++kc) {
            float4 e0 = *(const float4*)(ep + kc * 32);
            float4 e1 = *(const float4*)(ep + kc * 32 + 4);
            half8 a;
            a[0] = (_Float16)e0.x; a[1] = (_Float16)e0.y;
            a[2] = (_Float16)e0.z; a[3] = (_Float16)e0.w;
            a[4] = (_Float16)e1.x; a[5] = (_Float16)e1.y;
            a[6] = (_Float16)e1.z; a[7] = (_Float16)e1.w;
            const int dbase = q * 8 + kc * 32;
            #pragma unroll
            for (int tt = 0; tt < 7; ++tt) {
                half8 b = *(const half8*)&B_s[(tt * 16 + row) * BDP + dbase];
                acc[tt] = __builtin_amdgcn_mfma_f32_16x16x32_f16(a, b, acc[tt], 0, 0, 0);
            }
        }

        // ---- 7. Combine: part[r] = sum_m s[l,m]*dw[m,l]; C layout col=m, row=q*4+r ----
        float part[4] = {0.f, 0.f, 0.f, 0.f};
        #pragma unroll
        for (int tt = 0; tt < 7; ++tt) {
            int m = tt * 16 + row;
            #pragma unroll
            for (int r = 0; r < 4; ++r) {
                float dwv = (float)dw_s[m * DWP + lbase + r];
                part[r] += acc[tt][r] * dwv;
            }
        }
        #pragma unroll
        for (int off = 1; off < 16; off <<= 1) {
            #pragma unroll
            for (int r = 0; r < 4; ++r) part[r] += __shfl_xor(part[r], off);
        }
        if (row == 0) {
            #pragma unroll
            for (int r = 0; r < 4; ++r) {
                int l = l0 + lbase + r;
                if (l < L_) out[(size_t)n * L_ + l] = part[r];
            }
        }

        if (tn < NTILES) __syncthreads();  // dw_s fully consumed before next overwrite
    }
}

extern "C" void kernel_launch(void* const* d_in, const int* in_sizes, int n_in,
                              void* d_out, int out_size, void* d_ws, size_t ws_size,
                              hipStream_t stream) {
    const float* self_attn  = (const float*)d_in[0];
    const float* self_delta = (const float*)d_in[1];
    // d_in[2] = traj_len (int32) — unused by the reference computation
    const float* emb_table  = (const float*)d_in[3];
    const float* value_w    = (const float*)d_in[4];
    float* out = (float*)d_out;

    dim3 grid(NBX, N_);
    attn_fused_kernel<<<grid, NT, 0, stream>>>(self_attn, self_delta, emb_table, value_w, out);
}

// Round 3
// 338.382 us; speedup vs baseline: 1.0727x; 1.0455x over previous
//
#include <hip/hip_runtime.h>

#define N_    16
#define M_    100
#define L_    10000
#define EMB_  128
#define TL    64     // l-tile
#define NT    256    // 4 waves
#define MT    112    // m padded to 7 tiles of 16
#define BDP   136    // B_s row stride in f16 (128+8)
#define DWP   68     // dw_s row stride in f16 (64+4)
#define NIT   25     // (TL*M_)/NT float4 loads per thread per tile
#define NTILES 157   // ceil(L_/TL)
#define NBX   32     // blocks per n -> 512 blocks total = exactly 2/CU, 64/XCD

typedef _Float16 half8   __attribute__((ext_vector_type(8)));
typedef _Float16 half4v  __attribute__((ext_vector_type(4)));
typedef float    floatx4 __attribute__((ext_vector_type(4)));

// Persistent-strided blocks + ROLLING delta prefetch: the consume of dv[it]
// (reduce -> dw_s) immediately re-issues dv[it] for tile t+NBX, so the
// per-thread vmcnt never drains below ~24 — the 256 MB delta stream never
// stops at tile boundaries (the previous version drained to 0 every tile).
__global__ __launch_bounds__(NT, 2) void attn_fused_kernel(
    const float* __restrict__ self_attn,   // (N, M, EMB)
    const float* __restrict__ self_delta,  // (N, M, L, 4)
    const float* __restrict__ emb_table,   // (L+1, EMB)
    const float* __restrict__ value_w,     // (M)
    float* __restrict__ out)               // (N, L)
{
    __shared__ _Float16 B_s[MT * BDP];    // attnw[m][d], f16   (30.5 KB)
    __shared__ _Float16 dw_s[MT * DWP];   // dw[m][ll],  f16   (15.2 KB)

    const int n   = blockIdx.y;
    const int bx  = blockIdx.x;
    const int tid = threadIdx.x;

    const floatx4* dp = (const floatx4*)self_delta + (size_t)n * M_ * L_;

    // ---- 1. Issue tile bx's delta loads (deep MLP under the staging).
    //         Nontemporal: 256 MB stream-once — keep emb/attn resident in L2.
    floatx4 dv[NIT];
    #pragma unroll
    for (int it = 0; it < NIT; ++it) {
        int idx = tid + it * NT;
        int ll  = idx & (TL - 1);
        int m   = idx >> 6;
        int l   = bx * TL + ll;
        if (l >= L_) l = L_ - 1;              // clamped addr; zeroed at consume
        dv[it] = __builtin_nontemporal_load(&dp[(size_t)m * L_ + l]);
    }

    // ---- 2. Zero pad rows m=100..111 of both LDS panels (once) ----
    for (int i = tid; i < 12 * BDP; i += NT)
        B_s[100 * BDP + i] = (_Float16)0.f;
    for (int i = tid; i < 12 * DWP; i += NT)
        dw_s[100 * DWP + i] = (_Float16)0.f;

    // ---- 3. Stage B_s = attn[n,m,:] * w[m] as f16, ONCE per block (L2-hot) ----
    const float4* ap = (const float4*)(self_attn + (size_t)n * M_ * EMB_);
    for (int i = tid; i < M_ * EMB_ / 4; i += NT) {
        int m  = i >> 5;            // (i*4) / 128
        int d4 = (i & 31) * 4;
        float wv  = value_w[m];
        float4 av = ap[i];
        half4v h;
        h[0] = (_Float16)(av.x * wv); h[1] = (_Float16)(av.y * wv);
        h[2] = (_Float16)(av.z * wv); h[3] = (_Float16)(av.w * wv);
        *(half4v*)&B_s[m * BDP + d4] = h;   // 8B-aligned ds_write_b64
    }

    const int lane  = tid & 63;
    const int wid   = tid >> 6;     // wave's 16-row l-subtile
    const int row   = lane & 15;
    const int q     = lane >> 4;
    const int lbase = wid * 16 + q * 4;

    for (int t = bx; t < NTILES; t += NBX) {
        const int l0 = t * TL;
        const int tn = t + NBX;
        const bool have_next = (tn < NTILES);

        // ---- 4. Rolling consume+reissue: reduce dv[it] -> dw_s, then
        //         immediately refill dv[it] with tile tn's element. The
        //         register anti-dependence keeps ~24 loads in flight
        //         throughout — no vmcnt(0) drain at tile boundaries.
        #pragma unroll
        for (int it = 0; it < NIT; ++it) {
            int idx = tid + it * NT;
            int ll  = idx & (TL - 1);
            int m   = idx >> 6;
            floatx4 d4 = dv[it];
            int l = l0 + ll;
            float s = (l < L_) ? (d4.x + d4.y + d4.z + d4.w) : 0.f;
            dw_s[m * DWP + ll] = (_Float16)s;
            // reissue (uniform broadcast of dp[0] when no next tile: one
            // L2-hot line, branch-free, never consumed)
            int ln = tn * TL + ll;
            if (ln >= L_) ln = L_ - 1;
            size_t off = have_next ? ((size_t)m * L_ + ln) : 0;
            dv[it] = __builtin_nontemporal_load(&dp[off]);
        }
        __syncthreads();   // dw_s (and, first iter, B_s) visible to all waves

        // ---- 5. MFMA: s[l,m] tiles. A = emb rows (f32->f16, L2-hot), B = B_s ----
        floatx4 acc[7];
        #pragma unroll
        for (int tt = 0; tt < 7; ++tt) acc[tt] = (floatx4){0.f, 0.f, 0.f, 0.f};

        int al = l0 + wid * 16 + row + 1;        // emb row = l+1
        if (al > L_) al = L_;                    // clamp (dw=0 kills the product)
        const float* ep = emb_table + (size_t)al * EMB_ + q * 8;

        #pragma unroll
        for (int kc = 0; kc < 4; ++kc) {
            float4 e0 = *(const float4*)(ep + kc * 32);
            float4 e1 = *(const float4*)(ep + kc * 32 + 4);
            half8 a;
            a[0] = (_Float16)e0.x; a[1] = (_Float16)e0.y;
            a[2] = (_Float16)e0.z; a[3] = (_Float16)e0.w;
            a[4] = (_Float16)e1.x; a[5] = (_Float16)e1.y;
            a[6] = (_Float16)e1.z; a[7] = (_Float16)e1.w;
            const int dbase = q * 8 + kc * 32;
            #pragma unroll
            for (int tt = 0; tt < 7; ++tt) {
                half8 b = *(const half8*)&B_s[(tt * 16 + row) * BDP + dbase];
                acc[tt] = __builtin_amdgcn_mfma_f32_16x16x32_f16(a, b, acc[tt], 0, 0, 0);
            }
        }

        // ---- 6. Combine: part[r] = sum_m s[l,m]*dw[m,l]; C layout col=m, row=q*4+r ----
        float part[4] = {0.f, 0.f, 0.f, 0.f};
        #pragma unroll
        for (int tt = 0; tt < 7; ++tt) {
            int m = tt * 16 + row;
            half4v dwv4 = *(const half4v*)&dw_s[m * DWP + lbase];  // 8B-aligned ds_read_b64
            #pragma unroll
            for (int r = 0; r < 4; ++r)
                part[r] += acc[tt][r] * (float)dwv4[r];
        }
        #pragma unroll
        for (int off = 1; off < 16; off <<= 1) {
            #pragma unroll
            for (int r = 0; r < 4; ++r) part[r] += __shfl_xor(part[r], off);
        }
        if (row == 0) {
            #pragma unroll
            for (int r = 0; r < 4; ++r) {
                int l = l0 + lbase + r;
                if (l < L_) out[(size_t)n * L_ + l] = part[r];
            }
        }

        if (have_next) __syncthreads();  // dw_s fully consumed before next overwrite
    }
}

extern "C" void kernel_launch(void* const* d_in, const int* in_sizes, int n_in,
                              void* d_out, int out_size, void* d_ws, size_t ws_size,
                              hipStream_t stream) {
    const float* self_attn  = (const float*)d_in[0];
    const float* self_delta = (const float*)d_in[1];
    // d_in[2] = traj_len (int32) — unused by the reference computation
    const float* emb_table  = (const float*)d_in[3];
    const float* value_w    = (const float*)d_in[4];
    float* out = (float*)d_out;

    dim3 grid(NBX, N_);
    attn_fused_kernel<<<grid, NT, 0, stream>>>(self_attn, self_delta, emb_table, value_w, out);
}